// Round 3
// baseline (96.162 us; speedup 1.0000x reference)
//
#include <hip/hip_runtime.h>
#include <hip/hip_bf16.h>
#include <stdint.h>

typedef __attribute__((ext_vector_type(8))) short short8;
typedef __attribute__((ext_vector_type(8))) unsigned short ushort8;
typedef __attribute__((ext_vector_type(4))) float f32x4;

#define BSZ 512
#define DFIELD 16384
#define KSPLIT 96
#define KCHUNK 512
#define BK 64
#define TSIZE (256 * 256)
#define NPAIRS 130816.0f

__device__ __forceinline__ ushort f2bf(float f) {
    uint32_t u = __float_as_uint(f);
    uint32_t r = (u + 0x7fffu + ((u >> 16) & 1u)) >> 16;
    return (ushort)r;
}

__device__ __forceinline__ float bf2f(ushort u) {
    return __uint_as_float(((uint32_t)u) << 16);
}

// 4 fp32 -> 4 bf16 via 2 HW pack-converts
__device__ __forceinline__ uint2 cvt_f4(float4 v) {
    uint2 r;
    asm("v_cvt_pk_bf16_f32 %0, %1, %2" : "=v"(r.x) : "v"(v.x), "v"(v.y));
    asm("v_cvt_pk_bf16_f32 %0, %1, %2" : "=v"(r.y) : "v"(v.z), "v"(v.w));
    return r;
}

// 256x256 tiles over the 512x512 gram; 3 tiles: 0=(0,0) 1=(0,1) 2=(1,1).
// Diag tiles stage one panel (A==B) -> total logical reads 201 MB fp32.
__global__ __launch_bounds__(512, 2) void gemm_kernel(
    const float* __restrict__ e, const float* __restrict__ a,
    const float* __restrict__ c, ushort* __restrict__ P) {
    const int tt = blockIdx.x / KSPLIT;
    const int ks = blockIdx.x % KSPLIT;
    const int ti = (tt == 2) ? 1 : 0;
    const int tj = (tt == 0) ? 0 : 1;
    const bool diag = (tt != 1);

    const int kbase = ks * KCHUNK;
    const float* X = (kbase < DFIELD) ? e : (kbase < 2 * DFIELD ? a : c);
    const int koff0 = kbase & (DFIELD - 1);

    __shared__ ushort As[256 * 64];
    __shared__ ushort Bs[256 * 64];

    const int t = threadIdx.x;
    const int lane = t & 63, wid = t >> 6;
    const int wm = wid >> 2, wn = wid & 3;          // wave tile: 128 rows x 64 cols
    // diag tiles: waves (wm=1, wn<2) cover rows 128-255 x cols 0-127 -> strictly lower, skip
    const bool skipw = diag && (wm == 1) && (wn < 2);

    const f32x4 zero = {0.f, 0.f, 0.f, 0.f};
    f32x4 acc[8][4];
#pragma unroll
    for (int m = 0; m < 8; ++m)
#pragma unroll
        for (int n = 0; n < 4; ++n) acc[m][n] = zero;

    const int srow = t >> 3;          // 0..63
    const int scg  = (t & 7) * 8;     // k offset (floats), 8-elem granules
    const float* pa = X + (size_t)(ti * 256 + srow) * DFIELD + koff0 + scg;
    const float* pb = X + (size_t)(tj * 256 + srow) * DFIELD + koff0 + scg;

    for (int kt = 0; kt < KCHUNK / BK; ++kt) {
        const int kk = kt * BK;
        // ---- stage A: 256 rows x 64 k ----
#pragma unroll
        for (int rep = 0; rep < 4; ++rep) {
            const int r = srow + rep * 64;
            const float* p = pa + (size_t)(rep * 64) * DFIELD + kk;
            float4 v0 = reinterpret_cast<const float4*>(p)[0];
            float4 v1 = reinterpret_cast<const float4*>(p)[1];
            uint2 w0 = cvt_f4(v0);
            uint2 w1 = cvt_f4(v1);
            uint4 w = {w0.x, w0.y, w1.x, w1.y};
            const int g = (t & 7) ^ (r & 7);
            *reinterpret_cast<uint4*>(&As[r * 64 + g * 8]) = w;
        }
        if (!diag) {
#pragma unroll
            for (int rep = 0; rep < 4; ++rep) {
                const int r = srow + rep * 64;
                const float* p = pb + (size_t)(rep * 64) * DFIELD + kk;
                float4 v0 = reinterpret_cast<const float4*>(p)[0];
                float4 v1 = reinterpret_cast<const float4*>(p)[1];
                uint2 w0 = cvt_f4(v0);
                uint2 w1 = cvt_f4(v1);
                uint4 w = {w0.x, w0.y, w1.x, w1.y};
                const int g = (t & 7) ^ (r & 7);
                *reinterpret_cast<uint4*>(&Bs[r * 64 + g * 8]) = w;
            }
        }
        __syncthreads();
        const ushort* Bsrc = diag ? As : Bs;
        if (!skipw) {
#pragma unroll
            for (int half = 0; half < 2; ++half) {
                short8 af[8], bfv[4];
                const int kq = half * 4 + (lane >> 4);
#pragma unroll
                for (int m = 0; m < 8; ++m) {
                    const int row = wm * 128 + m * 16 + (lane & 15);
                    const int g = kq ^ (row & 7);
                    af[m] = *reinterpret_cast<const short8*>(&As[row * 64 + g * 8]);
                }
#pragma unroll
                for (int n = 0; n < 4; ++n) {
                    const int row = wn * 64 + n * 16 + (lane & 15);
                    const int g = kq ^ (row & 7);
                    bfv[n] = *reinterpret_cast<const short8*>(&Bsrc[row * 64 + g * 8]);
                }
#pragma unroll
                for (int m = 0; m < 8; ++m)
#pragma unroll
                    for (int n = 0; n < 4; ++n)
                        acc[m][n] = __builtin_amdgcn_mfma_f32_16x16x32_bf16(
                            af[m], bfv[n], acc[m][n], 0, 0, 0);
            }
        }
        __syncthreads();
    }

    if (!skipw) {
        ushort* Pk = P + ((size_t)tt * KSPLIT + ks) * TSIZE;
        const int ci = (lane >> 4) * 4, cj = lane & 15;
#pragma unroll
        for (int m = 0; m < 8; ++m)
#pragma unroll
            for (int n = 0; n < 4; ++n)
#pragma unroll
                for (int r = 0; r < 4; ++r) {
                    const int li = wm * 128 + m * 16 + ci + r;
                    const int lj = wn * 64 + n * 16 + cj;
                    Pk[li * 256 + lj] = f2bf(acc[m][n][r]);
                }
    }
}

__global__ void diag_kernel(const ushort* __restrict__ P, float* __restrict__ DIAG) {
    const int i = blockIdx.x * blockDim.x + threadIdx.x;
    if (i < BSZ) {
        const int tt = (i >> 8) ? 2 : 0;
        const int li = i & 255;
        const ushort* base = P + (size_t)tt * KSPLIT * TSIZE + li * 257;
        float s = 0.f;
#pragma unroll 8
        for (int ks = 0; ks < KSPLIT; ++ks)
            s += bf2f(base[(size_t)ks * TSIZE]);
        DIAG[i] = s;
    }
}

__global__ __launch_bounds__(256) void pair_kernel(
    const ushort* __restrict__ P, const float* __restrict__ DIAG,
    const int* __restrict__ tg, float* __restrict__ LP) {
    const int t = threadIdx.x;
    const int gid = blockIdx.x * 256 + t;
    const int i = gid >> 6;
    const int j0 = (gid & 63) * 8;
    float local = 0.f;
    if (j0 + 7 > i) {
        int tt, li, lj0;
        if (i < 256) {
            tt = (j0 >= 256) ? 1 : 0;
            li = i;
            lj0 = (j0 >= 256) ? (j0 - 256) : j0;
        } else {
            tt = 2; li = i - 256; lj0 = j0 - 256;
        }
        const ushort* base = P + (size_t)tt * KSPLIT * TSIZE + li * 256 + lj0;
        float s[8];
#pragma unroll
        for (int u = 0; u < 8; ++u) s[u] = 0.f;
        for (int ks = 0; ks < KSPLIT; ++ks) {
            ushort8 v = *reinterpret_cast<const ushort8*>(base + (size_t)ks * TSIZE);
#pragma unroll
            for (int u = 0; u < 8; ++u) s[u] += bf2f(v[u]);
        }
        const float di = DIAG[i];
        const int ti_lbl = tg[i];
#pragma unroll
        for (int u = 0; u < 8; ++u) {
            const int j = j0 + u;
            if (j > i) {
                const float d = (di + DIAG[j] - 2.f * s[u]) * (1.f / 16384.f);
                local += (ti_lbl == tg[j]) ? d : fmaxf(1.f - d, 0.f);
            }
        }
    }
#pragma unroll
    for (int off = 32; off; off >>= 1) local += __shfl_down(local, off, 64);
    __shared__ float red[4];
    const int lane = t & 63, wid = t >> 6;
    if (lane == 0) red[wid] = local;
    __syncthreads();
    if (t == 0) LP[blockIdx.x] = red[0] + red[1] + red[2] + red[3];
}

__global__ void final_kernel(const float* __restrict__ LP, float* __restrict__ out) {
    const int t = threadIdx.x;  // 128 threads
    float v = LP[t];
#pragma unroll
    for (int off = 32; off; off >>= 1) v += __shfl_down(v, off, 64);
    __shared__ float red[2];
    if ((t & 63) == 0) red[t >> 6] = v;
    __syncthreads();
    if (t == 0) out[0] = (red[0] + red[1]) * (1.f / NPAIRS);
}

extern "C" void kernel_launch(void* const* d_in, const int* in_sizes, int n_in,
                              void* d_out, int out_size, void* d_ws, size_t ws_size,
                              hipStream_t stream) {
    const float* e  = (const float*)d_in[0];
    const float* a  = (const float*)d_in[1];
    const float* c  = (const float*)d_in[2];
    const int*   tg = (const int*)d_in[3];

    ushort* P    = (ushort*)d_ws;  // 3 * 96 * 65536 bf16 = 37.75 MB
    float*  DIAG = (float*)((char*)d_ws + (size_t)3 * KSPLIT * TSIZE * 2);
    float*  LP   = DIAG + BSZ;
    float*  out  = (float*)d_out;

    gemm_kernel<<<dim3(3 * KSPLIT), dim3(512), 0, stream>>>(e, a, c, P);
    diag_kernel<<<dim3(2), dim3(256), 0, stream>>>(P, DIAG);
    pair_kernel<<<dim3(128), dim3(256), 0, stream>>>(P, DIAG, tg, LP);
    final_kernel<<<dim3(1), dim3(128), 0, stream>>>(LP, out);
}

// Round 4
// 64.714 us; speedup vs baseline: 1.4860x; 1.4860x over previous
//
#include <hip/hip_runtime.h>
#include <hip/hip_bf16.h>
#include <stdint.h>

typedef __attribute__((ext_vector_type(8))) short short8;
typedef __attribute__((ext_vector_type(8))) unsigned short ushort8;
typedef __attribute__((ext_vector_type(4))) float f32x4;

#define BSZ 512
#define DFIELD 16384
#define KSPLIT 48
#define KCHUNK 1024
#define BK 64
#define NKSTEP (KCHUNK / BK)   /* 16 */
#define NTILE 10
#define TSIZE (128 * 128)
#define SKEW 5
#define NPAIRS 130816.0f

__device__ __forceinline__ ushort f2bf(float f) {
    uint32_t u = __float_as_uint(f);
    uint32_t r = (u + 0x7fffu + ((u >> 16) & 1u)) >> 16;
    return (ushort)r;
}

__device__ __forceinline__ float bf2f(ushort u) {
    return __uint_as_float(((uint32_t)u) << 16);
}

__device__ __forceinline__ uint2 cvt_f4(float4 v) {
    uint2 r;
    asm("v_cvt_pk_bf16_f32 %0, %1, %2" : "=v"(r.x) : "v"(v.x), "v"(v.y));
    asm("v_cvt_pk_bf16_f32 %0, %1, %2" : "=v"(r.y) : "v"(v.z), "v"(v.w));
    return r;
}

// 128x128 tiles (10 upper-tri), KSPLIT=48, double-buffered LDS with
// register prefetch: loads for step k+1 issue before MFMA of step k.
__global__ __launch_bounds__(256, 2) void gemm_kernel(
    const float* __restrict__ e, const float* __restrict__ a,
    const float* __restrict__ c, ushort* __restrict__ P) {
    const int tile = blockIdx.x / KSPLIT;
    const int ks   = blockIdx.x % KSPLIT;
    int ti = 0, rem = tile;
    while (rem >= 4 - ti) { rem -= 4 - ti; ++ti; }
    const int tj = ti + rem;
    const bool diag = (ti == tj);
    const int brow = ti * 128, bcol = tj * 128;

    const int kbase = ks * KCHUNK;
    const float* X = (kbase < DFIELD) ? e : (kbase < 2 * DFIELD ? a : c);
    const int koff0 = kbase & (DFIELD - 1);

    __shared__ ushort As[2][128 * 64];
    __shared__ ushort Bs[2][128 * 64];

    const int t = threadIdx.x;
    const int lane = t & 63, wid = t >> 6;
    const int wr = (wid >> 1) * 64, wc = (wid & 1) * 64;
    const bool skipw = diag && (wr == 64) && (wc == 0);  // strictly-lower wave

    const int srow = t >> 3;       // 0..31
    const int sg   = t & 7;        // 8-float granule index within BK
    const float* pa = X + (size_t)(brow + srow) * DFIELD + koff0 + sg * 8;
    const float* pb = X + (size_t)(bcol + srow) * DFIELD + koff0 + sg * 8;

    const f32x4 zero = {0.f, 0.f, 0.f, 0.f};
    f32x4 acc[4][4];
#pragma unroll
    for (int m = 0; m < 4; ++m)
#pragma unroll
        for (int n = 0; n < 4; ++n) acc[m][n] = zero;

    float4 ra[8], rb[8];

    auto LOAD = [&](int kk) {
#pragma unroll
        for (int rep = 0; rep < 4; ++rep) {
            const float* p = pa + (size_t)(rep * 32) * DFIELD + kk;
            ra[2 * rep]     = reinterpret_cast<const float4*>(p)[0];
            ra[2 * rep + 1] = reinterpret_cast<const float4*>(p)[1];
        }
        if (!diag) {
#pragma unroll
            for (int rep = 0; rep < 4; ++rep) {
                const float* p = pb + (size_t)(rep * 32) * DFIELD + kk;
                rb[2 * rep]     = reinterpret_cast<const float4*>(p)[0];
                rb[2 * rep + 1] = reinterpret_cast<const float4*>(p)[1];
            }
        }
    };
    auto CVTWR = [&](int buf) {
#pragma unroll
        for (int rep = 0; rep < 4; ++rep) {
            const int r = srow + rep * 32;
            uint2 w0 = cvt_f4(ra[2 * rep]);
            uint2 w1 = cvt_f4(ra[2 * rep + 1]);
            uint4 w = {w0.x, w0.y, w1.x, w1.y};
            const int g = sg ^ (r & 7);
            *reinterpret_cast<uint4*>(&As[buf][r * 64 + g * 8]) = w;
        }
        if (!diag) {
#pragma unroll
            for (int rep = 0; rep < 4; ++rep) {
                const int r = srow + rep * 32;
                uint2 w0 = cvt_f4(rb[2 * rep]);
                uint2 w1 = cvt_f4(rb[2 * rep + 1]);
                uint4 w = {w0.x, w0.y, w1.x, w1.y};
                const int g = sg ^ (r & 7);
                *reinterpret_cast<uint4*>(&Bs[buf][r * 64 + g * 8]) = w;
            }
        }
    };

    LOAD(0);
    CVTWR(0);
    __syncthreads();

    for (int kt = 0; kt < NKSTEP; ++kt) {
        const int cur = kt & 1;
        if (kt + 1 < NKSTEP) LOAD((kt + 1) * BK);   // prefetch under MFMA
        if (!skipw) {
            const ushort* Asrc = As[cur];
            const ushort* Bsrc = diag ? As[cur] : Bs[cur];
#pragma unroll
            for (int half = 0; half < 2; ++half) {
                short8 af[4], bfv[4];
                const int kq = half * 4 + (lane >> 4);
#pragma unroll
                for (int m = 0; m < 4; ++m) {
                    const int row = wr + m * 16 + (lane & 15);
                    const int g = kq ^ (row & 7);
                    af[m] = *reinterpret_cast<const short8*>(&Asrc[row * 64 + g * 8]);
                }
#pragma unroll
                for (int n = 0; n < 4; ++n) {
                    const int row = wc + n * 16 + (lane & 15);
                    const int g = kq ^ (row & 7);
                    bfv[n] = *reinterpret_cast<const short8*>(&Bsrc[row * 64 + g * 8]);
                }
#pragma unroll
                for (int m = 0; m < 4; ++m)
#pragma unroll
                    for (int n = 0; n < 4; ++n)
                        acc[m][n] = __builtin_amdgcn_mfma_f32_16x16x32_bf16(
                            af[m], bfv[n], acc[m][n], 0, 0, 0);
            }
        }
        if (kt + 1 < NKSTEP) CVTWR(cur ^ 1);
        __syncthreads();
    }

    if (!skipw) {
        ushort* Pk = P + (size_t)(tile * KSPLIT + ks) * TSIZE;
        const int ci = (lane >> 4) * 4, cj = lane & 15;
#pragma unroll
        for (int m = 0; m < 4; ++m)
#pragma unroll
            for (int n = 0; n < 4; ++n)
#pragma unroll
                for (int r = 0; r < 4; ++r) {
                    const int li = wr + m * 16 + ci + r;
                    const int lj = wc + n * 16 + cj;
                    const int pr = (li + SKEW * ks) & 127;  // de-alias channels
                    Pk[pr * 128 + lj] = f2bf(acc[m][n][r]);
                }
    }
}

// Collapse 48 bf16 slices -> fp32 G[10][128][128]; extract DIAG inline.
__global__ __launch_bounds__(256) void reducek_kernel(
    const ushort* __restrict__ P, float* __restrict__ G, float* __restrict__ DIAG) {
    const int tx = threadIdx.x;
    const int tile  = blockIdx.x >> 3;   // 80 blocks: 10 tiles x 8 chunks
    const int chunk = blockIdx.x & 7;
    const int li  = chunk * 16 + (tx >> 4);
    const int lj0 = (tx & 15) * 8;
    float s[8];
#pragma unroll
    for (int u = 0; u < 8; ++u) s[u] = 0.f;
    const ushort* base = P + (size_t)tile * KSPLIT * TSIZE + lj0;
    for (int k = 0; k < KSPLIT; ++k) {
        const int pr = (li + SKEW * k) & 127;
        ushort8 v = *reinterpret_cast<const ushort8*>(base + (size_t)k * TSIZE + pr * 128);
#pragma unroll
        for (int u = 0; u < 8; ++u) s[u] += bf2f(v[u]);
    }
    float* g = G + (size_t)tile * TSIZE + li * 128 + lj0;
    float4 g0 = {s[0], s[1], s[2], s[3]};
    float4 g1 = {s[4], s[5], s[6], s[7]};
    reinterpret_cast<float4*>(g)[0] = g0;
    reinterpret_cast<float4*>(g)[1] = g1;
    int dti = -1;
    if (tile == 0) dti = 0; else if (tile == 4) dti = 1;
    else if (tile == 7) dti = 2; else if (tile == 9) dti = 3;
    if (dti >= 0 && li >= lj0 && li < lj0 + 8)
        DIAG[dti * 128 + li] = s[li - lj0];
}

__global__ __launch_bounds__(256) void pair_kernel(
    const float* __restrict__ G, const float* __restrict__ DIAG,
    const int* __restrict__ tg, float* __restrict__ LP) {
    const int t = threadIdx.x;
    const int gid = blockIdx.x * 256 + t;   // 128 blocks
    const int i = gid >> 6;
    const int j0 = (gid & 63) * 8;
    float local = 0.f;
    if (j0 + 7 > i) {
        const int ti2 = i >> 7, tj2 = j0 >> 7;
        const int tidx = (ti2 * (9 - ti2)) / 2 + (tj2 - ti2);
        const int li = i & 127, lj0 = j0 & 127;
        const float* g = G + (size_t)tidx * TSIZE + li * 128 + lj0;
        float4 g0 = reinterpret_cast<const float4*>(g)[0];
        float4 g1 = reinterpret_cast<const float4*>(g)[1];
        float gv[8] = {g0.x, g0.y, g0.z, g0.w, g1.x, g1.y, g1.z, g1.w};
        const float di = DIAG[i];
        const int lbl = tg[i];
#pragma unroll
        for (int u = 0; u < 8; ++u) {
            const int j = j0 + u;
            if (j > i) {
                const float d = (di + DIAG[j] - 2.f * gv[u]) * (1.f / 16384.f);
                local += (lbl == tg[j]) ? d : fmaxf(1.f - d, 0.f);
            }
        }
    }
#pragma unroll
    for (int off = 32; off; off >>= 1) local += __shfl_down(local, off, 64);
    __shared__ float red[4];
    const int lane = t & 63, wid = t >> 6;
    if (lane == 0) red[wid] = local;
    __syncthreads();
    if (t == 0) LP[blockIdx.x] = red[0] + red[1] + red[2] + red[3];
}

__global__ void final_kernel(const float* __restrict__ LP, float* __restrict__ out) {
    const int t = threadIdx.x;  // 128 threads
    float v = LP[t];
#pragma unroll
    for (int off = 32; off; off >>= 1) v += __shfl_down(v, off, 64);
    __shared__ float red[2];
    if ((t & 63) == 0) red[t >> 6] = v;
    __syncthreads();
    if (t == 0) out[0] = (red[0] + red[1]) * (1.f / NPAIRS);
}

extern "C" void kernel_launch(void* const* d_in, const int* in_sizes, int n_in,
                              void* d_out, int out_size, void* d_ws, size_t ws_size,
                              hipStream_t stream) {
    const float* e  = (const float*)d_in[0];
    const float* a  = (const float*)d_in[1];
    const float* c  = (const float*)d_in[2];
    const int*   tg = (const int*)d_in[3];

    ushort* P    = (ushort*)d_ws;                                   // 15.7 MB
    float*  G    = (float*)((char*)d_ws + (size_t)NTILE * KSPLIT * TSIZE * 2);
    float*  DIAG = G + (size_t)NTILE * TSIZE;                       // 512 floats
    float*  LP   = DIAG + BSZ;                                      // 128 floats
    float*  out  = (float*)d_out;

    gemm_kernel<<<dim3(NTILE * KSPLIT), dim3(256), 0, stream>>>(e, a, c, P);
    reducek_kernel<<<dim3(80), dim3(256), 0, stream>>>(P, G, DIAG);
    pair_kernel<<<dim3(128), dim3(256), 0, stream>>>(G, DIAG, tg, LP);
    final_kernel<<<dim3(1), dim3(128), 0, stream>>>(LP, out);
}